// Round 6
// baseline (4572.515 us; speedup 1.0000x reference)
//
#include <hip/hip_runtime.h>
#include <hip/hip_bf16.h>

#define N_NODES 16384
#define N_EDGES 262144
#define NGRAPH  128
#define NPG     128
#define DMODEL  256
#define NLAYER  5
#define NHEAD   4
#define DHEAD   64

// ---------------- output convert helper ----------------
template<typename T> __device__ inline T cvt_out(float v);
template<> __device__ inline float cvt_out<float>(float v) { return v; }
template<> __device__ inline __hip_bfloat16 cvt_out<__hip_bfloat16>(float v) { return __float2bfloat16(v); }

// ---------------- GEMM: C[M,N] = act( (A (+A2)) @ W^T + bias ) ----------------
// A: [M,K] row-major, W: [N,K] row-major. M%128==0, N%128==0, K%8==0.
// ACT: 0=none, 1=GELU(erf), 2=ReLU
template<int ACT, bool FUSE, typename OutT>
__global__ __launch_bounds__(256) void gemm_k(
    int M, int N, int K,
    const float* __restrict__ A, const float* __restrict__ A2,
    const float* __restrict__ W, const float* __restrict__ bias,
    OutT* __restrict__ C)
{
    __shared__ float As[8][128];
    __shared__ float Bs[8][128];
    const int t = threadIdx.x;
    const int tx = t & 15, ty = t >> 4;
    const int row0 = blockIdx.y * 128, col0 = blockIdx.x * 128;

    float acc[8][8];
    #pragma unroll
    for (int i = 0; i < 8; ++i)
        #pragma unroll
        for (int j = 0; j < 8; ++j) acc[i][j] = 0.f;

    const int l  = t * 4;
    const int ar = l >> 3, ac = l & 7;   // ac in {0,4}

    for (int k0 = 0; k0 < K; k0 += 8) {
        float4 av = *reinterpret_cast<const float4*>(A + (size_t)(row0 + ar) * K + k0 + ac);
        if (FUSE) {
            float4 a2 = *reinterpret_cast<const float4*>(A2 + (size_t)(row0 + ar) * K + k0 + ac);
            av.x += a2.x; av.y += a2.y; av.z += a2.z; av.w += a2.w;
        }
        float4 bv = *reinterpret_cast<const float4*>(W + (size_t)(col0 + ar) * K + k0 + ac);
        As[ac + 0][ar] = av.x; As[ac + 1][ar] = av.y; As[ac + 2][ar] = av.z; As[ac + 3][ar] = av.w;
        Bs[ac + 0][ar] = bv.x; Bs[ac + 1][ar] = bv.y; Bs[ac + 2][ar] = bv.z; Bs[ac + 3][ar] = bv.w;
        __syncthreads();
        #pragma unroll
        for (int kk = 0; kk < 8; ++kk) {
            float a[8], b[8];
            #pragma unroll
            for (int i = 0; i < 8; ++i) a[i] = As[kk][ty + i * 16];
            #pragma unroll
            for (int j = 0; j < 8; ++j) b[j] = Bs[kk][tx + j * 16];
            #pragma unroll
            for (int i = 0; i < 8; ++i)
                #pragma unroll
                for (int j = 0; j < 8; ++j) acc[i][j] += a[i] * b[j];
        }
        __syncthreads();
    }

    #pragma unroll
    for (int i = 0; i < 8; ++i) {
        const int m = row0 + ty + i * 16;
        #pragma unroll
        for (int j = 0; j < 8; ++j) {
            const int n = col0 + tx + j * 16;
            float v = acc[i][j];
            if (bias) v += bias[n];
            if (ACT == 1) v = 0.5f * v * (1.0f + erff(v * 0.70710678118654752f));
            if (ACT == 2) v = fmaxf(v, 0.f);
            C[(size_t)m * N + n] = cvt_out<OutT>(v);
        }
    }
}

// ---------------- CSR build (by dst) ----------------
__global__ void count_k(const int* __restrict__ dst, int* __restrict__ counts)
{
    for (int i = blockIdx.x * blockDim.x + threadIdx.x; i < N_EDGES; i += gridDim.x * blockDim.x)
        atomicAdd(&counts[dst[i]], 1);
}

__global__ void scan_k(const int* __restrict__ counts, int* __restrict__ rowptr, int* __restrict__ cursor)
{
    __shared__ int part[256];
    __shared__ int base_s[257];
    const int t = threadIdx.x;
    int sum = 0;
    for (int i = 0; i < 64; ++i) sum += counts[t * 64 + i];
    part[t] = sum;
    __syncthreads();
    if (t == 0) {
        int acc = 0;
        for (int i = 0; i < 256; ++i) { base_s[i] = acc; acc += part[i]; }
        base_s[256] = acc;
    }
    __syncthreads();
    int run = base_s[t];
    for (int i = 0; i < 64; ++i) {
        const int idx = t * 64 + i;
        rowptr[idx] = run; cursor[idx] = run;
        run += counts[idx];
    }
    if (t == 255) rowptr[N_NODES] = base_s[256];
}

__global__ void fill_k(const int* __restrict__ dst, int* __restrict__ cursor, int* __restrict__ elist)
{
    for (int i = blockIdx.x * blockDim.x + threadIdx.x; i < N_EDGES; i += gridDim.x * blockDim.x) {
        const int p = atomicAdd(&cursor[dst[i]], 1);
        elist[p] = i;
    }
}

// ---------------- GINE aggregation: agg[n,:] = sum_{e: dst=n} relu(h[src]+e) ----------------
// PRE=true : e precomputed (bf16 cache e_b). PRE=false: recompute e row on the fly
// with We ([256,64] f32) staged in LDS ([256][65] pad -> (t+k)%32 banks, 2 lanes/bank = free).
template<bool PRE>
__global__ __launch_bounds__(256) void agg_k(
    const float* __restrict__ h, const __hip_bfloat16* __restrict__ e_b,
    const float* __restrict__ edge_attr, const float* __restrict__ We,
    const int* __restrict__ src, const int* __restrict__ rowptr,
    const int* __restrict__ elist, float* __restrict__ agg)
{
    const int n = blockIdx.x, t = threadIdx.x;
    const int beg = rowptr[n], end = rowptr[n + 1];
    float acc = 0.f;
    if (PRE) {
        for (int j = beg; j < end; ++j) {
            const int eid = elist[j];
            const int s   = src[eid];
            const float v = h[(size_t)s * DMODEL + t] + __bfloat162float(e_b[(size_t)eid * DMODEL + t]);
            acc += fmaxf(v, 0.f);
        }
    } else {
        __shared__ float We_s[256][65];
        __shared__ float ea_s[64];
        for (int idx = t; idx < 256 * 64; idx += 256)
            We_s[idx >> 6][idx & 63] = We[idx];
        __syncthreads();
        for (int j = beg; j < end; ++j) {   // beg/end uniform across block -> barriers safe
            const int eid = elist[j];
            const int s   = src[eid];
            if (t < 64) ea_s[t] = edge_attr[(size_t)eid * 64 + t];
            __syncthreads();
            float dot = 0.f;
            #pragma unroll
            for (int k = 0; k < 64; ++k) dot += ea_s[k] * We_s[t][k];
            acc += fmaxf(h[(size_t)s * DMODEL + t] + dot, 0.f);
            __syncthreads();
        }
    }
    agg[(size_t)n * DMODEL + t] = acc;
}

// ---------------- graph LayerNorm: out = LN_graph(x1 + x2)*g+b (+ addout) ----------------
// Safe with out aliasing x1 or x2 (per-block-exclusive slice; all stats reads precede
// barriers; write loop reads element i before writing it).
__global__ __launch_bounds__(256) void ln_k(
    const float* __restrict__ x1, const float* __restrict__ x2,
    const float* __restrict__ gamma, const float* __restrict__ beta,
    const float* __restrict__ addout, float* __restrict__ out)
{
    const int b = blockIdx.x, t = threadIdx.x;
    const size_t base = (size_t)b * (NPG * DMODEL);
    const float* p1 = x1 + base;
    const float* p2 = x2 + base;
    float s = 0.f, ss = 0.f;
    for (int i = t; i < NPG * DMODEL; i += 256) {
        const float v = p1[i] + p2[i];
        s += v; ss += v * v;
    }
    __shared__ float rs[256], rq[256];
    rs[t] = s; rq[t] = ss;
    __syncthreads();
    for (int off = 128; off > 0; off >>= 1) {
        if (t < off) { rs[t] += rs[t + off]; rq[t] += rq[t + off]; }
        __syncthreads();
    }
    const float mu   = rs[0] * (1.f / (NPG * DMODEL));
    const float var  = rq[0] * (1.f / (NPG * DMODEL)) - mu * mu;
    const float rstd = rsqrtf(var + 1e-5f);
    const float* pa = addout ? addout + base : nullptr;
    float* po = out + base;
    for (int i = t; i < NPG * DMODEL; i += 256) {
        const float v = p1[i] + p2[i];
        float y = (v - mu) * rstd * gamma[i & (DMODEL - 1)] + beta[i & (DMODEL - 1)];
        if (pa) y += pa[i];
        po[i] = y;
    }
}

// ---------------- per-(graph,head) attention ----------------
// qkv: [N, 768]; out: [N, 256] (head hh occupies cols hh*64..hh*64+63)
// Static LDS 129.5 KiB (gfx950 allows 160 KiB; 128 KiB static verified in plain HIP).
__global__ __launch_bounds__(256) void attn_k(const float* __restrict__ qkv, float* __restrict__ attnout)
{
    __shared__ float s_s[128][129];
    __shared__ float q_s[128][65];
    __shared__ float kv_s[128][65];
    const int blk = blockIdx.x;
    const int b = blk >> 2, hh = blk & 3;
    const int t = threadIdx.x;
    const size_t base = (size_t)b * NPG * (3 * DMODEL) + hh * DHEAD;

    // load q, k
    for (int l = t; l < 128 * 64; l += 256) {
        const int r = l >> 6, c = l & 63;
        q_s[r][c]  = qkv[base + (size_t)r * 768 + c];
        kv_s[r][c] = qkv[base + 256 + (size_t)r * 768 + c];
    }
    __syncthreads();

    // scores: 4x4 register tiles, 4 tiles/thread
    #pragma unroll
    for (int it = 0; it < 4; ++it) {
        const int tt = t + 256 * it;
        const int tr = (tt & 31) * 4;
        const int tc = (tt >> 5) * 4;
        float acc[4][4];
        #pragma unroll
        for (int i = 0; i < 4; ++i)
            #pragma unroll
            for (int j = 0; j < 4; ++j) acc[i][j] = 0.f;
        for (int d = 0; d < 64; ++d) {
            float qa[4], kb[4];
            #pragma unroll
            for (int i = 0; i < 4; ++i) qa[i] = q_s[tr + i][d];
            #pragma unroll
            for (int j = 0; j < 4; ++j) kb[j] = kv_s[tc + j][d];
            #pragma unroll
            for (int i = 0; i < 4; ++i)
                #pragma unroll
                for (int j = 0; j < 4; ++j) acc[i][j] += qa[i] * kb[j];
        }
        #pragma unroll
        for (int i = 0; i < 4; ++i)
            #pragma unroll
            for (int j = 0; j < 4; ++j) s_s[tr + i][tc + j] = acc[i][j] * 0.125f;
    }
    __syncthreads();

    // softmax: pair of lanes per row (t>>1 = row, t&1 = half)
    {
        const int r = t >> 1, ch = (t & 1) * 64;
        float mx = -1e30f;
        for (int cc = 0; cc < 64; ++cc) mx = fmaxf(mx, s_s[r][ch + cc]);
        mx = fmaxf(mx, __shfl_xor(mx, 1));
        float sum = 0.f;
        for (int cc = 0; cc < 64; ++cc) {
            const float pv = expf(s_s[r][ch + cc] - mx);
            s_s[r][ch + cc] = pv; sum += pv;
        }
        sum += __shfl_xor(sum, 1);
        const float inv = 1.f / sum;
        for (int cc = 0; cc < 64; ++cc) s_s[r][ch + cc] *= inv;
    }
    __syncthreads();

    // load v over k
    for (int l = t; l < 128 * 64; l += 256) {
        const int r = l >> 6, c = l & 63;
        kv_s[r][c] = qkv[base + 512 + (size_t)r * 768 + c];
    }
    __syncthreads();

    // PV: 4x4 register tiles, 2 tiles/thread
    #pragma unroll
    for (int it = 0; it < 2; ++it) {
        const int tt  = t + 256 * it;          // 0..511
        const int tr  = (tt & 31) * 4;         // rows
        const int tdh = (tt >> 5) * 4;         // dh cols (0..60)
        float acc[4][4];
        #pragma unroll
        for (int i = 0; i < 4; ++i)
            #pragma unroll
            for (int j = 0; j < 4; ++j) acc[i][j] = 0.f;
        for (int c = 0; c < 128; ++c) {
            float pa[4], vb[4];
            #pragma unroll
            for (int i = 0; i < 4; ++i) pa[i] = s_s[tr + i][c];
            #pragma unroll
            for (int j = 0; j < 4; ++j) vb[j] = kv_s[c][tdh + j];
            #pragma unroll
            for (int i = 0; i < 4; ++i)
                #pragma unroll
                for (int j = 0; j < 4; ++j) acc[i][j] += pa[i] * vb[j];
        }
        #pragma unroll
        for (int i = 0; i < 4; ++i) {
            float* op = attnout + ((size_t)(b * NPG + tr + i)) * DMODEL + hh * DHEAD + tdh;
            #pragma unroll
            for (int j = 0; j < 4; ++j) op[j] = acc[i][j];
        }
    }
}

// ---------------- finalize: copy h to out, global_add_pool ----------------
__global__ __launch_bounds__(256) void finalize_k(const float* __restrict__ h,
                                                  float* __restrict__ out_h,
                                                  float* __restrict__ out_glob)
{
    const int b = blockIdx.x, d = threadIdx.x;
    float s = 0.f;
    for (int n = 0; n < NPG; ++n) {
        const size_t idx = ((size_t)b * NPG + n) * DMODEL + d;
        const float v = h[idx];
        s += v;
        out_h[idx] = v;
    }
    out_glob[(size_t)b * DMODEL + d] = s;
}

// ---------------- launch ----------------
extern "C" void kernel_launch(void* const* d_in, const int* in_sizes, int n_in,
                              void* d_out, int out_size, void* d_ws, size_t ws_size,
                              hipStream_t stream)
{
    const float* x          = (const float*)d_in[0];
    const float* edge_attr  = (const float*)d_in[1];
    const int*   eidx       = (const int*)d_in[2];
    const float* node_emb_w = (const float*)d_in[4];
    const float* edge_emb_w = (const float*)d_in[5];
    const float* conv_w1    = (const float*)d_in[6];
    const float* conv_b1    = (const float*)d_in[7];
    const float* conv_w2    = (const float*)d_in[8];
    const float* conv_b2    = (const float*)d_in[9];
    const float* attn_in_w  = (const float*)d_in[10];
    const float* attn_in_b  = (const float*)d_in[11];
    const float* attn_out_w = (const float*)d_in[12];
    const float* attn_out_b = (const float*)d_in[13];
    const float* n1_g = (const float*)d_in[14];
    const float* n1_b = (const float*)d_in[15];
    const float* n2_g = (const float*)d_in[16];
    const float* n2_b = (const float*)d_in[17];
    const float* n3_g = (const float*)d_in[18];
    const float* n3_b = (const float*)d_in[19];
    const float* mlp_w1 = (const float*)d_in[20];
    const float* mlp_b1 = (const float*)d_in[21];
    const float* mlp_w2 = (const float*)d_in[22];
    const float* mlp_b2 = (const float*)d_in[23];
    const int* src = eidx;
    const int* dst = eidx + N_EDGES;

    char* p = (char*)d_ws;
    auto alloc = [&](size_t bytes) -> void* {
        void* r = (void*)p;
        p += (bytes + 255) & ~(size_t)255;
        return r;
    };
    // Mandatory buffers: 113.2 MiB total
    float* h  = (float*)alloc((size_t)N_NODES * DMODEL * 4);
    float* bA = (float*)alloc((size_t)N_NODES * DMODEL * 4);
    float* bB = (float*)alloc((size_t)N_NODES * DMODEL * 4);
    float* bC = (float*)alloc((size_t)N_NODES * DMODEL * 4);
    float* Q  = (float*)alloc((size_t)N_NODES * 3 * DMODEL * 4);   // qkv; also mlp-mid [N,512]
    int* counts = (int*)alloc((size_t)N_NODES * 4);
    int* rowptr = (int*)alloc((size_t)(N_NODES + 1) * 4);
    int* cursor = (int*)alloc((size_t)N_NODES * 4);
    int* elist  = (int*)alloc((size_t)N_EDGES * 4);
    // Optional 128 MiB edge-embedding cache. ws_size is constant across calls,
    // so this branch is deterministic (graph-capture safe).
    const bool big = ws_size >= (size_t)253000000;
    __hip_bfloat16* e_b = big ? (__hip_bfloat16*)alloc((size_t)N_EDGES * DMODEL * 2) : nullptr;

    // CSR build (per call: ws is re-poisoned)
    hipMemsetAsync(counts, 0, (size_t)N_NODES * 4, stream);
    count_k<<<512, 256, 0, stream>>>(dst, counts);
    scan_k<<<1, 256, 0, stream>>>(counts, rowptr, cursor);
    fill_k<<<512, 256, 0, stream>>>(dst, cursor, elist);

    // embeddings
    if (big)
        gemm_k<0, false, __hip_bfloat16><<<dim3(DMODEL / 128, N_EDGES / 128), 256, 0, stream>>>(
            N_EDGES, DMODEL, 64, edge_attr, nullptr, edge_emb_w, nullptr, e_b);
    gemm_k<0, false, float><<<dim3(DMODEL / 128, N_NODES / 128), 256, 0, stream>>>(
        N_NODES, DMODEL, 128, x, nullptr, node_emb_w, nullptr, h);

    for (int l = 0; l < NLAYER; ++l) {
        const float* w1  = conv_w1 + (size_t)l * DMODEL * DMODEL;
        const float* b1  = conv_b1 + (size_t)l * DMODEL;
        const float* w2  = conv_w2 + (size_t)l * DMODEL * DMODEL;
        const float* b2  = conv_b2 + (size_t)l * DMODEL;
        const float* inw = attn_in_w + (size_t)l * 3 * DMODEL * DMODEL;
        const float* inb = attn_in_b + (size_t)l * 3 * DMODEL;
        const float* ow  = attn_out_w + (size_t)l * DMODEL * DMODEL;
        const float* ob  = attn_out_b + (size_t)l * DMODEL;
        const float* mw1 = mlp_w1 + (size_t)l * 2 * DMODEL * DMODEL;
        const float* mb1 = mlp_b1 + (size_t)l * 2 * DMODEL;
        const float* mw2 = mlp_w2 + (size_t)l * 2 * DMODEL * DMODEL;
        const float* mb2 = mlp_b2 + (size_t)l * DMODEL;

        // GINEConv
        if (big)
            agg_k<true ><<<N_NODES, 256, 0, stream>>>(h, e_b, edge_attr, edge_emb_w, src, rowptr, elist, bA);
        else
            agg_k<false><<<N_NODES, 256, 0, stream>>>(h, e_b, edge_attr, edge_emb_w, src, rowptr, elist, bA);
        gemm_k<1, true, float><<<dim3(2, 128), 256, 0, stream>>>(
            N_NODES, DMODEL, DMODEL, h, bA, w1, b1, bB);                       // gelu((h+agg)@w1^T+b1)
        gemm_k<0, false, float><<<dim3(2, 128), 256, 0, stream>>>(
            N_NODES, DMODEL, DMODEL, bB, nullptr, w2, b2, bA);                 // @w2^T+b2
        ln_k<<<NGRAPH, 256, 0, stream>>>(bA, h, n1_g + (size_t)l * DMODEL, n1_b + (size_t)l * DMODEL,
                                         nullptr, bC);                          // h1
        // attention
        gemm_k<0, false, float><<<dim3(6, 128), 256, 0, stream>>>(
            N_NODES, 3 * DMODEL, DMODEL, h, nullptr, inw, inb, Q);             // qkv
        attn_k<<<NGRAPH * NHEAD, 256, 0, stream>>>(Q, bB);                     // attn (pre-proj)
        gemm_k<0, false, float><<<dim3(2, 128), 256, 0, stream>>>(
            N_NODES, DMODEL, DMODEL, bB, nullptr, ow, ob, bA);                 // out-proj
        ln_k<<<NGRAPH, 256, 0, stream>>>(bA, h, n2_g + (size_t)l * DMODEL, n2_b + (size_t)l * DMODEL,
                                         bC, h);                                // h = out = h1 + h2 (in-place)
        // MLP
        gemm_k<2, false, float><<<dim3(4, 128), 256, 0, stream>>>(
            N_NODES, 2 * DMODEL, DMODEL, h, nullptr, mw1, mb1, Q);             // relu(out@mw1^T+mb1)
        gemm_k<0, false, float><<<dim3(2, 128), 256, 0, stream>>>(
            N_NODES, DMODEL, 2 * DMODEL, Q, nullptr, mw2, mb2, bA);            // @mw2^T+mb2
        ln_k<<<NGRAPH, 256, 0, stream>>>(h, bA, n3_g + (size_t)l * DMODEL, n3_b + (size_t)l * DMODEL,
                                         nullptr, h);                           // h = norm3(out+mlp) (in-place)
    }

    finalize_k<<<NGRAPH, 256, 0, stream>>>(h, (float*)d_out, (float*)d_out + (size_t)N_NODES * DMODEL);
}

// Round 8
// 3637.399 us; speedup vs baseline: 1.2571x; 1.2571x over previous
//
#include <hip/hip_runtime.h>
#include <hip/hip_bf16.h>

#define N_NODES 16384
#define N_EDGES 262144
#define NGRAPH  128
#define NPG     128
#define DMODEL  256
#define NLAYER  5
#define NHEAD   4
#define DHEAD   64

// ---------------- output convert helper ----------------
template<typename T> __device__ inline T cvt_out(float v);
template<> __device__ inline float cvt_out<float>(float v) { return v; }
template<> __device__ inline __hip_bfloat16 cvt_out<__hip_bfloat16>(float v) { return __float2bfloat16(v); }

// ---------------- GEMM: C[M,N] = act( (A (+A2)) @ W^T + bias ) ----------------
// A: [M,K] row-major, W: [N,K] row-major. M%128==0, N%128==0, K%8==0.
// ACT: 0=none, 1=GELU(erf), 2=ReLU
template<int ACT, bool FUSE, typename OutT>
__global__ __launch_bounds__(256) void gemm_k(
    int M, int N, int K,
    const float* __restrict__ A, const float* __restrict__ A2,
    const float* __restrict__ W, const float* __restrict__ bias,
    OutT* __restrict__ C)
{
    __shared__ float As[8][128];
    __shared__ float Bs[8][128];
    const int t = threadIdx.x;
    const int tx = t & 15, ty = t >> 4;
    const int row0 = blockIdx.y * 128, col0 = blockIdx.x * 128;

    float acc[8][8];
    #pragma unroll
    for (int i = 0; i < 8; ++i)
        #pragma unroll
        for (int j = 0; j < 8; ++j) acc[i][j] = 0.f;

    const int l  = t * 4;
    const int ar = l >> 3, ac = l & 7;   // ac in {0,4}

    for (int k0 = 0; k0 < K; k0 += 8) {
        float4 av = *reinterpret_cast<const float4*>(A + (size_t)(row0 + ar) * K + k0 + ac);
        if (FUSE) {
            float4 a2 = *reinterpret_cast<const float4*>(A2 + (size_t)(row0 + ar) * K + k0 + ac);
            av.x += a2.x; av.y += a2.y; av.z += a2.z; av.w += a2.w;
        }
        float4 bv = *reinterpret_cast<const float4*>(W + (size_t)(col0 + ar) * K + k0 + ac);
        As[ac + 0][ar] = av.x; As[ac + 1][ar] = av.y; As[ac + 2][ar] = av.z; As[ac + 3][ar] = av.w;
        Bs[ac + 0][ar] = bv.x; Bs[ac + 1][ar] = bv.y; Bs[ac + 2][ar] = bv.z; Bs[ac + 3][ar] = bv.w;
        __syncthreads();
        #pragma unroll
        for (int kk = 0; kk < 8; ++kk) {
            float a[8], b[8];
            #pragma unroll
            for (int i = 0; i < 8; ++i) a[i] = As[kk][ty + i * 16];
            #pragma unroll
            for (int j = 0; j < 8; ++j) b[j] = Bs[kk][tx + j * 16];
            #pragma unroll
            for (int i = 0; i < 8; ++i)
                #pragma unroll
                for (int j = 0; j < 8; ++j) acc[i][j] += a[i] * b[j];
        }
        __syncthreads();
    }

    #pragma unroll
    for (int i = 0; i < 8; ++i) {
        const int m = row0 + ty + i * 16;
        #pragma unroll
        for (int j = 0; j < 8; ++j) {
            const int n = col0 + tx + j * 16;
            float v = acc[i][j];
            if (bias) v += bias[n];
            if (ACT == 1) v = 0.5f * v * (1.0f + erff(v * 0.70710678118654752f));
            if (ACT == 2) v = fmaxf(v, 0.f);
            C[(size_t)m * N + n] = cvt_out<OutT>(v);
        }
    }
}

// ---------------- CSR build (by dst) ----------------
__global__ void count_k(const int* __restrict__ dst, int* __restrict__ counts)
{
    for (int i = blockIdx.x * blockDim.x + threadIdx.x; i < N_EDGES; i += gridDim.x * blockDim.x)
        atomicAdd(&counts[dst[i]], 1);
}

__global__ void scan_k(const int* __restrict__ counts, int* __restrict__ rowptr, int* __restrict__ cursor)
{
    __shared__ int part[256];
    __shared__ int base_s[257];
    const int t = threadIdx.x;
    int sum = 0;
    for (int i = 0; i < 64; ++i) sum += counts[t * 64 + i];
    part[t] = sum;
    __syncthreads();
    if (t == 0) {
        int acc = 0;
        for (int i = 0; i < 256; ++i) { base_s[i] = acc; acc += part[i]; }
        base_s[256] = acc;
    }
    __syncthreads();
    int run = base_s[t];
    for (int i = 0; i < 64; ++i) {
        const int idx = t * 64 + i;
        rowptr[idx] = run; cursor[idx] = run;
        run += counts[idx];
    }
    if (t == 255) rowptr[N_NODES] = base_s[256];
}

__global__ void fill_k(const int* __restrict__ dst, int* __restrict__ cursor, int* __restrict__ elist)
{
    for (int i = blockIdx.x * blockDim.x + threadIdx.x; i < N_EDGES; i += gridDim.x * blockDim.x) {
        const int p = atomicAdd(&cursor[dst[i]], 1);
        elist[p] = i;
    }
}

// ---------------- GINE aggregation: agg[n,:] = sum_{e: dst=n} relu(h[src]+e) ----------------
template<bool PRE>
__global__ __launch_bounds__(256) void agg_k(
    const float* __restrict__ h, const __hip_bfloat16* __restrict__ e_b,
    const float* __restrict__ edge_attr, const float* __restrict__ We,
    const int* __restrict__ src, const int* __restrict__ rowptr,
    const int* __restrict__ elist, float* __restrict__ agg)
{
    const int n = blockIdx.x, t = threadIdx.x;
    const int beg = rowptr[n], end = rowptr[n + 1];
    float acc = 0.f;
    if (PRE) {
        for (int j = beg; j < end; ++j) {
            const int eid = elist[j];
            const int s   = src[eid];
            const float v = h[(size_t)s * DMODEL + t] + __bfloat162float(e_b[(size_t)eid * DMODEL + t]);
            acc += fmaxf(v, 0.f);
        }
    } else {
        __shared__ float We_s[256][65];
        __shared__ float ea_s[64];
        for (int idx = t; idx < 256 * 64; idx += 256)
            We_s[idx >> 6][idx & 63] = We[idx];
        __syncthreads();
        for (int j = beg; j < end; ++j) {   // beg/end uniform across block -> barriers safe
            const int eid = elist[j];
            const int s   = src[eid];
            if (t < 64) ea_s[t] = edge_attr[(size_t)eid * 64 + t];
            __syncthreads();
            float dot = 0.f;
            #pragma unroll
            for (int k = 0; k < 64; ++k) dot += ea_s[k] * We_s[t][k];
            acc += fmaxf(h[(size_t)s * DMODEL + t] + dot, 0.f);
            __syncthreads();
        }
    }
    agg[(size_t)n * DMODEL + t] = acc;
}

// ---------------- graph LayerNorm, split stats/apply (latency fix, r6) ----------------
// stats: 8 slices/graph x 256 thr, float4 loads, block-reduce -> 2 atomicAdd/block.
// stat[g] = {sum, sumsq} over x1+x2 of graph g. stat must be zeroed before launch.
__global__ __launch_bounds__(256) void ln_stats_k(
    const float* __restrict__ x1, const float* __restrict__ x2,
    float* __restrict__ stat)
{
    const int blk = blockIdx.x;          // g*8 + slice
    const int g = blk >> 3, sl = blk & 7;
    const int t = threadIdx.x;
    const float4* p1 = reinterpret_cast<const float4*>(x1) + (size_t)g * 8192 + sl * 1024;
    const float4* p2 = reinterpret_cast<const float4*>(x2) + (size_t)g * 8192 + sl * 1024;
    float s = 0.f, ss = 0.f;
    #pragma unroll
    for (int k = 0; k < 4; ++k) {
        const float4 a = p1[t + k * 256];
        const float4 b = p2[t + k * 256];
        const float v0 = a.x + b.x, v1 = a.y + b.y, v2 = a.z + b.z, v3 = a.w + b.w;
        s  += v0 + v1 + v2 + v3;
        ss += v0 * v0 + v1 * v1 + v2 * v2 + v3 * v3;
    }
    __shared__ float rs[256], rq[256];
    rs[t] = s; rq[t] = ss;
    __syncthreads();
    if (t < 128) { rs[t] += rs[t + 128]; rq[t] += rq[t + 128]; }
    __syncthreads();
    if (t < 64) {
        float a = rs[t] + rs[t + 64];
        float b = rq[t] + rq[t + 64];
        #pragma unroll
        for (int off = 32; off > 0; off >>= 1) {
            a += __shfl_down(a, off);
            b += __shfl_down(b, off);
        }
        if (t == 0) { atomicAdd(&stat[g * 2 + 0], a); atomicAdd(&stat[g * 2 + 1], b); }
    }
}

// apply: grid-stride float4, out = (x1+x2 - mu)*rstd*gamma+beta (+ addout).
// Alias-safe for out==x1/x2 (pure element-wise).
template<bool ADD>
__global__ __launch_bounds__(256) void ln_apply_k(
    const float* __restrict__ x1, const float* __restrict__ x2,
    const float* __restrict__ gamma, const float* __restrict__ beta,
    const float* __restrict__ addout, const float* __restrict__ stat,
    float* __restrict__ out)
{
    const int F = N_NODES * DMODEL / 4;   // 1,048,576 float4
    const float4* p1 = reinterpret_cast<const float4*>(x1);
    const float4* p2 = reinterpret_cast<const float4*>(x2);
    const float4* pg = reinterpret_cast<const float4*>(gamma);
    const float4* pb = reinterpret_cast<const float4*>(beta);
    const float4* pa = ADD ? reinterpret_cast<const float4*>(addout) : nullptr;
    float4* po = reinterpret_cast<float4*>(out);
    const float inv = 1.f / (NPG * DMODEL);
    for (int f = blockIdx.x * 256 + threadIdx.x; f < F; f += gridDim.x * 256) {
        const int g = f >> 13;            // 8192 float4 per graph
        const float mu   = stat[g * 2 + 0] * inv;
        const float var  = stat[g * 2 + 1] * inv - mu * mu;
        const float rstd = rsqrtf(var + 1e-5f);
        const float4 a = p1[f], b = p2[f];
        const float4 gm = pg[f & 63], bt = pb[f & 63];
        float4 y;
        y.x = (a.x + b.x - mu) * rstd * gm.x + bt.x;
        y.y = (a.y + b.y - mu) * rstd * gm.y + bt.y;
        y.z = (a.z + b.z - mu) * rstd * gm.z + bt.z;
        y.w = (a.w + b.w - mu) * rstd * gm.w + bt.w;
        if (ADD) {
            const float4 ao = pa[f];
            y.x += ao.x; y.y += ao.y; y.z += ao.z; y.w += ao.w;
        }
        po[f] = y;
    }
}

// ---------------- per-(graph,head) attention ----------------
// qkv: [N, 768]; out: [N, 256] (head hh occupies cols hh*64..hh*64+63)
// Static LDS 129.5 KiB (gfx950 allows 160 KiB).
__global__ __launch_bounds__(256) void attn_k(const float* __restrict__ qkv, float* __restrict__ attnout)
{
    __shared__ float s_s[128][129];
    __shared__ float q_s[128][65];
    __shared__ float kv_s[128][65];
    const int blk = blockIdx.x;
    const int b = blk >> 2, hh = blk & 3;
    const int t = threadIdx.x;
    const size_t base = (size_t)b * NPG * (3 * DMODEL) + hh * DHEAD;

    // load q, k
    for (int l = t; l < 128 * 64; l += 256) {
        const int r = l >> 6, c = l & 63;
        q_s[r][c]  = qkv[base + (size_t)r * 768 + c];
        kv_s[r][c] = qkv[base + 256 + (size_t)r * 768 + c];
    }
    __syncthreads();

    // scores: 4x4 register tiles, 4 tiles/thread
    #pragma unroll
    for (int it = 0; it < 4; ++it) {
        const int tt = t + 256 * it;
        const int tr = (tt & 31) * 4;
        const int tc = (tt >> 5) * 4;
        float acc[4][4];
        #pragma unroll
        for (int i = 0; i < 4; ++i)
            #pragma unroll
            for (int j = 0; j < 4; ++j) acc[i][j] = 0.f;
        for (int d = 0; d < 64; ++d) {
            float qa[4], kb[4];
            #pragma unroll
            for (int i = 0; i < 4; ++i) qa[i] = q_s[tr + i][d];
            #pragma unroll
            for (int j = 0; j < 4; ++j) kb[j] = kv_s[tc + j][d];
            #pragma unroll
            for (int i = 0; i < 4; ++i)
                #pragma unroll
                for (int j = 0; j < 4; ++j) acc[i][j] += qa[i] * kb[j];
        }
        #pragma unroll
        for (int i = 0; i < 4; ++i)
            #pragma unroll
            for (int j = 0; j < 4; ++j) s_s[tr + i][tc + j] = acc[i][j] * 0.125f;
    }
    __syncthreads();

    // softmax: pair of lanes per row
    {
        const int r = t >> 1, ch = (t & 1) * 64;
        float mx = -1e30f;
        for (int cc = 0; cc < 64; ++cc) mx = fmaxf(mx, s_s[r][ch + cc]);
        mx = fmaxf(mx, __shfl_xor(mx, 1));
        float sum = 0.f;
        for (int cc = 0; cc < 64; ++cc) {
            const float pv = expf(s_s[r][ch + cc] - mx);
            s_s[r][ch + cc] = pv; sum += pv;
        }
        sum += __shfl_xor(sum, 1);
        const float inv = 1.f / sum;
        for (int cc = 0; cc < 64; ++cc) s_s[r][ch + cc] *= inv;
    }
    __syncthreads();

    // load v over k
    for (int l = t; l < 128 * 64; l += 256) {
        const int r = l >> 6, c = l & 63;
        kv_s[r][c] = qkv[base + 512 + (size_t)r * 768 + c];
    }
    __syncthreads();

    // PV: 4x4 register tiles, 2 tiles/thread
    #pragma unroll
    for (int it = 0; it < 2; ++it) {
        const int tt  = t + 256 * it;
        const int tr  = (tt & 31) * 4;
        const int tdh = (tt >> 5) * 4;
        float acc[4][4];
        #pragma unroll
        for (int i = 0; i < 4; ++i)
            #pragma unroll
            for (int j = 0; j < 4; ++j) acc[i][j] = 0.f;
        for (int c = 0; c < 128; ++c) {
            float pa[4], vb[4];
            #pragma unroll
            for (int i = 0; i < 4; ++i) pa[i] = s_s[tr + i][c];
            #pragma unroll
            for (int j = 0; j < 4; ++j) vb[j] = kv_s[c][tdh + j];
            #pragma unroll
            for (int i = 0; i < 4; ++i)
                #pragma unroll
                for (int j = 0; j < 4; ++j) acc[i][j] += pa[i] * vb[j];
        }
        #pragma unroll
        for (int i = 0; i < 4; ++i) {
            float* op = attnout + ((size_t)(b * NPG + tr + i)) * DMODEL + hh * DHEAD + tdh;
            #pragma unroll
            for (int j = 0; j < 4; ++j) op[j] = acc[i][j];
        }
    }
}

// ---------------- global_add_pool: glob[g,d] += sum over 32-node quarter ----------------
// grid 512 = (g, quarter). glob must be zeroed before launch.
__global__ __launch_bounds__(256) void pool_k(const float* __restrict__ h, float* __restrict__ glob)
{
    const int blk = blockIdx.x;
    const int g = blk >> 2, q = blk & 3;
    const int d = threadIdx.x;
    const float* base = h + ((size_t)g * NPG + q * 32) * DMODEL + d;
    float s = 0.f;
    #pragma unroll
    for (int n = 0; n < 32; ++n) s += base[(size_t)n * DMODEL];
    atomicAdd(&glob[g * DMODEL + d], s);
}

// ---------------- launch ----------------
extern "C" void kernel_launch(void* const* d_in, const int* in_sizes, int n_in,
                              void* d_out, int out_size, void* d_ws, size_t ws_size,
                              hipStream_t stream)
{
    const float* x          = (const float*)d_in[0];
    const float* edge_attr  = (const float*)d_in[1];
    const int*   eidx       = (const int*)d_in[2];
    const float* node_emb_w = (const float*)d_in[4];
    const float* edge_emb_w = (const float*)d_in[5];
    const float* conv_w1    = (const float*)d_in[6];
    const float* conv_b1    = (const float*)d_in[7];
    const float* conv_w2    = (const float*)d_in[8];
    const float* conv_b2    = (const float*)d_in[9];
    const float* attn_in_w  = (const float*)d_in[10];
    const float* attn_in_b  = (const float*)d_in[11];
    const float* attn_out_w = (const float*)d_in[12];
    const float* attn_out_b = (const float*)d_in[13];
    const float* n1_g = (const float*)d_in[14];
    const float* n1_b = (const float*)d_in[15];
    const float* n2_g = (const float*)d_in[16];
    const float* n2_b = (const float*)d_in[17];
    const float* n3_g = (const float*)d_in[18];
    const float* n3_b = (const float*)d_in[19];
    const float* mlp_w1 = (const float*)d_in[20];
    const float* mlp_b1 = (const float*)d_in[21];
    const float* mlp_w2 = (const float*)d_in[22];
    const float* mlp_b2 = (const float*)d_in[23];
    const int* src = eidx;
    const int* dst = eidx + N_EDGES;

    char* p = (char*)d_ws;
    auto alloc = [&](size_t bytes) -> void* {
        void* r = (void*)p;
        p += (bytes + 255) & ~(size_t)255;
        return r;
    };
    // Mandatory buffers: ~113 MiB total
    float* h  = (float*)alloc((size_t)N_NODES * DMODEL * 4);
    float* bA = (float*)alloc((size_t)N_NODES * DMODEL * 4);
    float* bB = (float*)alloc((size_t)N_NODES * DMODEL * 4);
    float* bC = (float*)alloc((size_t)N_NODES * DMODEL * 4);
    float* Q  = (float*)alloc((size_t)N_NODES * 3 * DMODEL * 4);   // qkv; also mlp-mid [N,512]
    int* counts = (int*)alloc((size_t)N_NODES * 4);
    int* rowptr = (int*)alloc((size_t)(N_NODES + 1) * 4);
    int* cursor = (int*)alloc((size_t)N_NODES * 4);
    int* elist  = (int*)alloc((size_t)N_EDGES * 4);
    float* lnstat = (float*)alloc((size_t)3 * NLAYER * NGRAPH * 2 * 4);  // 15 LN slices
    // Optional 128 MiB edge-embedding cache (deterministic branch on ws_size).
    const bool big = ws_size >= (size_t)253000000;
    __hip_bfloat16* e_b = big ? (__hip_bfloat16*)alloc((size_t)N_EDGES * DMODEL * 2) : nullptr;

    float* out_h    = (float*)d_out;
    float* out_glob = (float*)d_out + (size_t)N_NODES * DMODEL;

    // zero-init (ws/d_out are re-poisoned each call)
    hipMemsetAsync(counts, 0, (size_t)N_NODES * 4, stream);
    hipMemsetAsync(lnstat, 0, (size_t)3 * NLAYER * NGRAPH * 2 * 4, stream);
    hipMemsetAsync(out_glob, 0, (size_t)NGRAPH * DMODEL * 4, stream);

    // CSR build
    count_k<<<512, 256, 0, stream>>>(dst, counts);
    scan_k<<<1, 256, 0, stream>>>(counts, rowptr, cursor);
    fill_k<<<512, 256, 0, stream>>>(dst, cursor, elist);

    // embeddings
    if (big)
        gemm_k<0, false, __hip_bfloat16><<<dim3(DMODEL / 128, N_EDGES / 128), 256, 0, stream>>>(
            N_EDGES, DMODEL, 64, edge_attr, nullptr, edge_emb_w, nullptr, e_b);
    gemm_k<0, false, float><<<dim3(DMODEL / 128, N_NODES / 128), 256, 0, stream>>>(
        N_NODES, DMODEL, 128, x, nullptr, node_emb_w, nullptr, h);

    // graph-LN helper: stats + apply
    auto launch_ln = [&](const float* x1, const float* x2, const float* g_, const float* b_,
                         const float* addout, float* out, int slice) {
        float* st = lnstat + (size_t)slice * NGRAPH * 2;
        ln_stats_k<<<NGRAPH * 8, 256, 0, stream>>>(x1, x2, st);
        if (addout)
            ln_apply_k<true ><<<2048, 256, 0, stream>>>(x1, x2, g_, b_, addout, st, out);
        else
            ln_apply_k<false><<<2048, 256, 0, stream>>>(x1, x2, g_, b_, nullptr, st, out);
    };

    for (int l = 0; l < NLAYER; ++l) {
        const float* w1  = conv_w1 + (size_t)l * DMODEL * DMODEL;
        const float* b1  = conv_b1 + (size_t)l * DMODEL;
        const float* w2  = conv_w2 + (size_t)l * DMODEL * DMODEL;
        const float* b2  = conv_b2 + (size_t)l * DMODEL;
        const float* inw = attn_in_w + (size_t)l * 3 * DMODEL * DMODEL;
        const float* inb = attn_in_b + (size_t)l * 3 * DMODEL;
        const float* ow  = attn_out_w + (size_t)l * DMODEL * DMODEL;
        const float* ob  = attn_out_b + (size_t)l * DMODEL;
        const float* mw1 = mlp_w1 + (size_t)l * 2 * DMODEL * DMODEL;
        const float* mb1 = mlp_b1 + (size_t)l * 2 * DMODEL;
        const float* mw2 = mlp_w2 + (size_t)l * 2 * DMODEL * DMODEL;
        const float* mb2 = mlp_b2 + (size_t)l * DMODEL;

        // GINEConv
        if (big)
            agg_k<true ><<<N_NODES, 256, 0, stream>>>(h, e_b, edge_attr, edge_emb_w, src, rowptr, elist, bA);
        else
            agg_k<false><<<N_NODES, 256, 0, stream>>>(h, e_b, edge_attr, edge_emb_w, src, rowptr, elist, bA);
        gemm_k<1, true, float><<<dim3(2, 128), 256, 0, stream>>>(
            N_NODES, DMODEL, DMODEL, h, bA, w1, b1, bB);                       // gelu((h+agg)@w1^T+b1)
        gemm_k<0, false, float><<<dim3(2, 128), 256, 0, stream>>>(
            N_NODES, DMODEL, DMODEL, bB, nullptr, w2, b2, bA);                 // @w2^T+b2
        launch_ln(bA, h, n1_g + (size_t)l * DMODEL, n1_b + (size_t)l * DMODEL,
                  nullptr, bC, 3 * l + 0);                                      // h1 = LN(z + h)
        // attention
        gemm_k<0, false, float><<<dim3(6, 128), 256, 0, stream>>>(
            N_NODES, 3 * DMODEL, DMODEL, h, nullptr, inw, inb, Q);             // qkv
        attn_k<<<NGRAPH * NHEAD, 256, 0, stream>>>(Q, bB);                     // attn (pre-proj)
        gemm_k<0, false, float><<<dim3(2, 128), 256, 0, stream>>>(
            N_NODES, DMODEL, DMODEL, bB, nullptr, ow, ob, bA);                 // out-proj
        launch_ln(bA, h, n2_g + (size_t)l * DMODEL, n2_b + (size_t)l * DMODEL,
                  bC, h, 3 * l + 1);                                            // h = h1 + LN(a + h)
        // MLP
        gemm_k<2, false, float><<<dim3(4, 128), 256, 0, stream>>>(
            N_NODES, 2 * DMODEL, DMODEL, h, nullptr, mw1, mb1, Q);             // relu(out@mw1^T+mb1)
        gemm_k<0, false, float><<<dim3(2, 128), 256, 0, stream>>>(
            N_NODES, DMODEL, 2 * DMODEL, Q, nullptr, mw2, mb2, bA);            // @mw2^T+mb2
        float* ln3_out = (l == NLAYER - 1) ? out_h : h;                        // final writes d_out
        launch_ln(h, bA, n3_g + (size_t)l * DMODEL, n3_b + (size_t)l * DMODEL,
                  nullptr, ln3_out, 3 * l + 2);                                 // h = LN(out + mlp)
    }

    pool_k<<<NGRAPH * 4, 256, 0, stream>>>(out_h, out_glob);
}

// Round 10
// 2207.556 us; speedup vs baseline: 2.0713x; 1.6477x over previous
//
#include <hip/hip_runtime.h>
#include <hip/hip_bf16.h>

#define N_NODES 16384
#define N_EDGES 262144
#define NGRAPH  128
#define NPG     128
#define DMODEL  256
#define NLAYER  5
#define NHEAD   4
#define DHEAD   64

using short8 = __attribute__((ext_vector_type(8))) short;
using f32x4  = __attribute__((ext_vector_type(4))) float;

// ---------------- output convert helper ----------------
template<typename T> __device__ inline T cvt_out(float v);
template<> __device__ inline float cvt_out<float>(float v) { return v; }
template<> __device__ inline __hip_bfloat16 cvt_out<__hip_bfloat16>(float v) { return __float2bfloat16(v); }

__device__ inline short f2bf(float f) {
    __hip_bfloat16 b = __float2bfloat16(f);
    return *reinterpret_cast<short*>(&b);
}

// ---------------- bf16 MFMA GEMM: C[M,N] = act( (A (+A2)) @ W^T + bias ) ----------------
// A: [M,K] f32 row-major, W: [N,K] f32 row-major. M%128==0, N%128==0, K%64==0.
// 128x128 tile, BK=64, 4 waves (64x64 quadrant each), mfma_f32_16x16x32_bf16.
// LDS rows 128B, XOR-swizzle byte ^= (row&7)<<4 (T2) -> conflict-free ds_read_b128.
// ACT: 0=none, 1=GELU(erf), 2=ReLU
template<int ACT, bool FUSE, typename OutT>
__global__ __launch_bounds__(256) void bgemm_k(
    int M, int N, int K,
    const float* __restrict__ A, const float* __restrict__ A2,
    const float* __restrict__ W, const float* __restrict__ bias,
    OutT* __restrict__ C)
{
    __shared__ __align__(16) short Asw[128 * 64];
    __shared__ __align__(16) short Bsw[128 * 64];
    const int t = threadIdx.x;
    const int row0 = blockIdx.y * 128, col0 = blockIdx.x * 128;
    const int lane = t & 63;
    const int wave = t >> 6;
    const int wm = (wave >> 1) * 64, wn = (wave & 1) * 64;   // quadrant origin
    const int fr = lane & 15;        // fragment row/col
    const int kg = lane >> 4;        // k-group (0..3)

    f32x4 acc[4][4];
    #pragma unroll
    for (int mi = 0; mi < 4; ++mi)
        #pragma unroll
        for (int ni = 0; ni < 4; ++ni)
            acc[mi][ni] = (f32x4){0.f, 0.f, 0.f, 0.f};

    // staging assignment: row = t&127, k-half = (t>>7)*32 (32 f32 per thread per tile)
    const int srow = t & 127;
    const int sh   = (t >> 7) * 32;
    const int sxor = (srow & 7) << 4;

    for (int k0 = 0; k0 < K; k0 += 64) {
        // ---- stage A (f32 -> bf16, swizzled) ----
        {
            const float4* ga = reinterpret_cast<const float4*>(A + (size_t)(row0 + srow) * K + k0 + sh);
            float4 v[8];
            #pragma unroll
            for (int i = 0; i < 8; ++i) v[i] = ga[i];
            if (FUSE) {
                const float4* g2 = reinterpret_cast<const float4*>(A2 + (size_t)(row0 + srow) * K + k0 + sh);
                #pragma unroll
                for (int i = 0; i < 8; ++i) {
                    float4 w2 = g2[i];
                    v[i].x += w2.x; v[i].y += w2.y; v[i].z += w2.z; v[i].w += w2.w;
                }
            }
            #pragma unroll
            for (int c = 0; c < 4; ++c) {
                short8 s8;
                const float* pv = reinterpret_cast<const float*>(&v[c * 2]);
                #pragma unroll
                for (int e = 0; e < 8; ++e) s8[e] = f2bf(pv[e]);
                const int byte = (sh * 2 + c * 16) ^ sxor;
                *reinterpret_cast<short8*>(&Asw[srow * 64 + (byte >> 1)]) = s8;
            }
        }
        // ---- stage B (W rows) ----
        {
            const float4* gb = reinterpret_cast<const float4*>(W + (size_t)(col0 + srow) * K + k0 + sh);
            float4 v[8];
            #pragma unroll
            for (int i = 0; i < 8; ++i) v[i] = gb[i];
            #pragma unroll
            for (int c = 0; c < 4; ++c) {
                short8 s8;
                const float* pv = reinterpret_cast<const float*>(&v[c * 2]);
                #pragma unroll
                for (int e = 0; e < 8; ++e) s8[e] = f2bf(pv[e]);
                const int byte = (sh * 2 + c * 16) ^ sxor;
                *reinterpret_cast<short8*>(&Bsw[srow * 64 + (byte >> 1)]) = s8;
            }
        }
        __syncthreads();

        // ---- MFMA: 2 k-halves x 4x4 frags ----
        #pragma unroll
        for (int kh = 0; kh < 2; ++kh) {
            short8 af[4], bf_[4];
            #pragma unroll
            for (int mi = 0; mi < 4; ++mi) {
                const int row  = wm + mi * 16 + fr;
                const int byte = (kh * 64 + kg * 16) ^ ((row & 7) << 4);
                af[mi] = *reinterpret_cast<const short8*>(&Asw[row * 64 + (byte >> 1)]);
            }
            #pragma unroll
            for (int ni = 0; ni < 4; ++ni) {
                const int row  = wn + ni * 16 + fr;
                const int byte = (kh * 64 + kg * 16) ^ ((row & 7) << 4);
                bf_[ni] = *reinterpret_cast<const short8*>(&Bsw[row * 64 + (byte >> 1)]);
            }
            #pragma unroll
            for (int mi = 0; mi < 4; ++mi)
                #pragma unroll
                for (int ni = 0; ni < 4; ++ni)
                    acc[mi][ni] = __builtin_amdgcn_mfma_f32_16x16x32_bf16(
                        af[mi], bf_[ni], acc[mi][ni], 0, 0, 0);
        }
        __syncthreads();
    }

    // ---- epilogue: D row = kg*4+r (m), col = fr (n)  [m89/m91 mapping] ----
    #pragma unroll
    for (int mi = 0; mi < 4; ++mi) {
        #pragma unroll
        for (int ni = 0; ni < 4; ++ni) {
            const int col = col0 + wn + ni * 16 + fr;
            const float bv = bias ? bias[col] : 0.f;
            #pragma unroll
            for (int r = 0; r < 4; ++r) {
                const int row = row0 + wm + mi * 16 + kg * 4 + r;
                float v = acc[mi][ni][r] + bv;
                if (ACT == 1) v = 0.5f * v * (1.0f + erff(v * 0.70710678118654752f));
                if (ACT == 2) v = fmaxf(v, 0.f);
                C[(size_t)row * N + col] = cvt_out<OutT>(v);
            }
        }
    }
}

// ---------------- CSR build (by dst) ----------------
__global__ void count_k(const int* __restrict__ dst, int* __restrict__ counts)
{
    for (int i = blockIdx.x * blockDim.x + threadIdx.x; i < N_EDGES; i += gridDim.x * blockDim.x)
        atomicAdd(&counts[dst[i]], 1);
}

__global__ void scan_k(const int* __restrict__ counts, int* __restrict__ rowptr, int* __restrict__ cursor)
{
    __shared__ int part[256];
    __shared__ int base_s[257];
    const int t = threadIdx.x;
    int sum = 0;
    for (int i = 0; i < 64; ++i) sum += counts[t * 64 + i];
    part[t] = sum;
    __syncthreads();
    if (t == 0) {
        int acc = 0;
        for (int i = 0; i < 256; ++i) { base_s[i] = acc; acc += part[i]; }
        base_s[256] = acc;
    }
    __syncthreads();
    int run = base_s[t];
    for (int i = 0; i < 64; ++i) {
        const int idx = t * 64 + i;
        rowptr[idx] = run; cursor[idx] = run;
        run += counts[idx];
    }
    if (t == 255) rowptr[N_NODES] = base_s[256];
}

__global__ void fill_k(const int* __restrict__ dst, int* __restrict__ cursor, int* __restrict__ elist)
{
    for (int i = blockIdx.x * blockDim.x + threadIdx.x; i < N_EDGES; i += gridDim.x * blockDim.x) {
        const int p = atomicAdd(&cursor[dst[i]], 1);
        elist[p] = i;
    }
}

// ---------------- GINE aggregation: agg[n,:] = sum_{e: dst=n} relu(h[src]+e) ----------------
template<bool PRE>
__global__ __launch_bounds__(256) void agg_k(
    const float* __restrict__ h, const __hip_bfloat16* __restrict__ e_b,
    const float* __restrict__ edge_attr, const float* __restrict__ We,
    const int* __restrict__ src, const int* __restrict__ rowptr,
    const int* __restrict__ elist, float* __restrict__ agg)
{
    const int n = blockIdx.x, t = threadIdx.x;
    const int beg = rowptr[n], end = rowptr[n + 1];
    float acc = 0.f;
    if (PRE) {
        for (int j = beg; j < end; ++j) {
            const int eid = elist[j];
            const int s   = src[eid];
            const float v = h[(size_t)s * DMODEL + t] + __bfloat162float(e_b[(size_t)eid * DMODEL + t]);
            acc += fmaxf(v, 0.f);
        }
    } else {
        __shared__ float We_s[256][65];
        __shared__ float ea_s[64];
        for (int idx = t; idx < 256 * 64; idx += 256)
            We_s[idx >> 6][idx & 63] = We[idx];
        __syncthreads();
        for (int j = beg; j < end; ++j) {   // beg/end uniform across block -> barriers safe
            const int eid = elist[j];
            const int s   = src[eid];
            if (t < 64) ea_s[t] = edge_attr[(size_t)eid * 64 + t];
            __syncthreads();
            float dot = 0.f;
            #pragma unroll
            for (int k = 0; k < 64; ++k) dot += ea_s[k] * We_s[t][k];
            acc += fmaxf(h[(size_t)s * DMODEL + t] + dot, 0.f);
            __syncthreads();
        }
    }
    agg[(size_t)n * DMODEL + t] = acc;
}

// ---------------- graph LayerNorm, split stats/apply ----------------
__global__ __launch_bounds__(256) void ln_stats_k(
    const float* __restrict__ x1, const float* __restrict__ x2,
    float* __restrict__ stat)
{
    const int blk = blockIdx.x;          // g*8 + slice
    const int g = blk >> 3, sl = blk & 7;
    const int t = threadIdx.x;
    const float4* p1 = reinterpret_cast<const float4*>(x1) + (size_t)g * 8192 + sl * 1024;
    const float4* p2 = reinterpret_cast<const float4*>(x2) + (size_t)g * 8192 + sl * 1024;
    float s = 0.f, ss = 0.f;
    #pragma unroll
    for (int k = 0; k < 4; ++k) {
        const float4 a = p1[t + k * 256];
        const float4 b = p2[t + k * 256];
        const float v0 = a.x + b.x, v1 = a.y + b.y, v2 = a.z + b.z, v3 = a.w + b.w;
        s  += v0 + v1 + v2 + v3;
        ss += v0 * v0 + v1 * v1 + v2 * v2 + v3 * v3;
    }
    __shared__ float rs[256], rq[256];
    rs[t] = s; rq[t] = ss;
    __syncthreads();
    if (t < 128) { rs[t] += rs[t + 128]; rq[t] += rq[t + 128]; }
    __syncthreads();
    if (t < 64) {
        float a = rs[t] + rs[t + 64];
        float b = rq[t] + rq[t + 64];
        #pragma unroll
        for (int off = 32; off > 0; off >>= 1) {
            a += __shfl_down(a, off);
            b += __shfl_down(b, off);
        }
        if (t == 0) { atomicAdd(&stat[g * 2 + 0], a); atomicAdd(&stat[g * 2 + 1], b); }
    }
}

template<bool ADD>
__global__ __launch_bounds__(256) void ln_apply_k(
    const float* __restrict__ x1, const float* __restrict__ x2,
    const float* __restrict__ gamma, const float* __restrict__ beta,
    const float* __restrict__ addout, const float* __restrict__ stat,
    float* __restrict__ out)
{
    const int F = N_NODES * DMODEL / 4;
    const float4* p1 = reinterpret_cast<const float4*>(x1);
    const float4* p2 = reinterpret_cast<const float4*>(x2);
    const float4* pg = reinterpret_cast<const float4*>(gamma);
    const float4* pb = reinterpret_cast<const float4*>(beta);
    const float4* pa = ADD ? reinterpret_cast<const float4*>(addout) : nullptr;
    float4* po = reinterpret_cast<float4*>(out);
    const float inv = 1.f / (NPG * DMODEL);
    for (int f = blockIdx.x * 256 + threadIdx.x; f < F; f += gridDim.x * 256) {
        const int g = f >> 13;
        const float mu   = stat[g * 2 + 0] * inv;
        const float var  = stat[g * 2 + 1] * inv - mu * mu;
        const float rstd = rsqrtf(var + 1e-5f);
        const float4 a = p1[f], b = p2[f];
        const float4 gm = pg[f & 63], bt = pb[f & 63];
        float4 y;
        y.x = (a.x + b.x - mu) * rstd * gm.x + bt.x;
        y.y = (a.y + b.y - mu) * rstd * gm.y + bt.y;
        y.z = (a.z + b.z - mu) * rstd * gm.z + bt.z;
        y.w = (a.w + b.w - mu) * rstd * gm.w + bt.w;
        if (ADD) {
            const float4 ao = pa[f];
            y.x += ao.x; y.y += ao.y; y.z += ao.z; y.w += ao.w;
        }
        po[f] = y;
    }
}

// ---------------- per-(graph,head) attention ----------------
__global__ __launch_bounds__(256) void attn_k(const float* __restrict__ qkv, float* __restrict__ attnout)
{
    __shared__ float s_s[128][129];
    __shared__ float q_s[128][65];
    __shared__ float kv_s[128][65];
    const int blk = blockIdx.x;
    const int b = blk >> 2, hh = blk & 3;
    const int t = threadIdx.x;
    const size_t base = (size_t)b * NPG * (3 * DMODEL) + hh * DHEAD;

    for (int l = t; l < 128 * 64; l += 256) {
        const int r = l >> 6, c = l & 63;
        q_s[r][c]  = qkv[base + (size_t)r * 768 + c];
        kv_s[r][c] = qkv[base + 256 + (size_t)r * 768 + c];
    }
    __syncthreads();

    #pragma unroll
    for (int it = 0; it < 4; ++it) {
        const int tt = t + 256 * it;
        const int tr = (tt & 31) * 4;
        const int tc = (tt >> 5) * 4;
        float acc[4][4];
        #pragma unroll
        for (int i = 0; i < 4; ++i)
            #pragma unroll
            for (int j = 0; j < 4; ++j) acc[i][j] = 0.f;
        for (int d = 0; d < 64; ++d) {
            float qa[4], kb[4];
            #pragma unroll
            for (int i = 0; i < 4; ++i) qa[i] = q_s[tr + i][d];
            #pragma unroll
            for (int j = 0; j < 4; ++j) kb[j] = kv_s[tc + j][d];
            #pragma unroll
            for (int i = 0; i < 4; ++i)
                #pragma unroll
                for (int j = 0; j < 4; ++j) acc[i][j] += qa[i] * kb[j];
        }
        #pragma unroll
        for (int i = 0; i < 4; ++i)
            #pragma unroll
            for (int j = 0; j < 4; ++j) s_s[tr + i][tc + j] = acc[i][j] * 0.125f;
    }
    __syncthreads();

    {
        const int r = t >> 1, ch = (t & 1) * 64;
        float mx = -1e30f;
        for (int cc = 0; cc < 64; ++cc) mx = fmaxf(mx, s_s[r][ch + cc]);
        mx = fmaxf(mx, __shfl_xor(mx, 1));
        float sum = 0.f;
        for (int cc = 0; cc < 64; ++cc) {
            const float pv = expf(s_s[r][ch + cc] - mx);
            s_s[r][ch + cc] = pv; sum += pv;
        }
        sum += __shfl_xor(sum, 1);
        const float inv = 1.f / sum;
        for (int cc = 0; cc < 64; ++cc) s_s[r][ch + cc] *= inv;
    }
    __syncthreads();

    for (int l = t; l < 128 * 64; l += 256) {
        const int r = l >> 6, c = l & 63;
        kv_s[r][c] = qkv[base + 512 + (size_t)r * 768 + c];
    }
    __syncthreads();

    #pragma unroll
    for (int it = 0; it < 2; ++it) {
        const int tt  = t + 256 * it;
        const int tr  = (tt & 31) * 4;
        const int tdh = (tt >> 5) * 4;
        float acc[4][4];
        #pragma unroll
        for (int i = 0; i < 4; ++i)
            #pragma unroll
            for (int j = 0; j < 4; ++j) acc[i][j] = 0.f;
        for (int c = 0; c < 128; ++c) {
            float pa[4], vb[4];
            #pragma unroll
            for (int i = 0; i < 4; ++i) pa[i] = s_s[tr + i][c];
            #pragma unroll
            for (int j = 0; j < 4; ++j) vb[j] = kv_s[c][tdh + j];
            #pragma unroll
            for (int i = 0; i < 4; ++i)
                #pragma unroll
                for (int j = 0; j < 4; ++j) acc[i][j] += pa[i] * vb[j];
        }
        #pragma unroll
        for (int i = 0; i < 4; ++i) {
            float* op = attnout + ((size_t)(b * NPG + tr + i)) * DMODEL + hh * DHEAD + tdh;
            #pragma unroll
            for (int j = 0; j < 4; ++j) op[j] = acc[i][j];
        }
    }
}

// ---------------- global_add_pool ----------------
__global__ __launch_bounds__(256) void pool_k(const float* __restrict__ h, float* __restrict__ glob)
{
    const int blk = blockIdx.x;
    const int g = blk >> 2, q = blk & 3;
    const int d = threadIdx.x;
    const float* base = h + ((size_t)g * NPG + q * 32) * DMODEL + d;
    float s = 0.f;
    #pragma unroll
    for (int n = 0; n < 32; ++n) s += base[(size_t)n * DMODEL];
    atomicAdd(&glob[g * DMODEL + d], s);
}

// ---------------- launch ----------------
extern "C" void kernel_launch(void* const* d_in, const int* in_sizes, int n_in,
                              void* d_out, int out_size, void* d_ws, size_t ws_size,
                              hipStream_t stream)
{
    const float* x          = (const float*)d_in[0];
    const float* edge_attr  = (const float*)d_in[1];
    const int*   eidx       = (const int*)d_in[2];
    const float* node_emb_w = (const float*)d_in[4];
    const float* edge_emb_w = (const float*)d_in[5];
    const float* conv_w1    = (const float*)d_in[6];
    const float* conv_b1    = (const float*)d_in[7];
    const float* conv_w2    = (const float*)d_in[8];
    const float* conv_b2    = (const float*)d_in[9];
    const float* attn_in_w  = (const float*)d_in[10];
    const float* attn_in_b  = (const float*)d_in[11];
    const float* attn_out_w = (const float*)d_in[12];
    const float* attn_out_b = (const float*)d_in[13];
    const float* n1_g = (const float*)d_in[14];
    const float* n1_b = (const float*)d_in[15];
    const float* n2_g = (const float*)d_in[16];
    const float* n2_b = (const float*)d_in[17];
    const float* n3_g = (const float*)d_in[18];
    const float* n3_b = (const float*)d_in[19];
    const float* mlp_w1 = (const float*)d_in[20];
    const float* mlp_b1 = (const float*)d_in[21];
    const float* mlp_w2 = (const float*)d_in[22];
    const float* mlp_b2 = (const float*)d_in[23];
    const int* src = eidx;
    const int* dst = eidx + N_EDGES;

    char* p = (char*)d_ws;
    auto alloc = [&](size_t bytes) -> void* {
        void* r = (void*)p;
        p += (bytes + 255) & ~(size_t)255;
        return r;
    };
    // Mandatory buffers: ~113 MiB total
    float* h  = (float*)alloc((size_t)N_NODES * DMODEL * 4);
    float* bA = (float*)alloc((size_t)N_NODES * DMODEL * 4);
    float* bB = (float*)alloc((size_t)N_NODES * DMODEL * 4);
    float* bC = (float*)alloc((size_t)N_NODES * DMODEL * 4);
    float* Q  = (float*)alloc((size_t)N_NODES * 3 * DMODEL * 4);   // qkv; also mlp-mid [N,512]
    int* counts = (int*)alloc((size_t)N_NODES * 4);
    int* rowptr = (int*)alloc((size_t)(N_NODES + 1) * 4);
    int* cursor = (int*)alloc((size_t)N_NODES * 4);
    int* elist  = (int*)alloc((size_t)N_EDGES * 4);
    float* lnstat = (float*)alloc((size_t)3 * NLAYER * NGRAPH * 2 * 4);  // 15 LN slices
    // Optional 128 MiB edge-embedding cache (deterministic branch on ws_size).
    const bool big = ws_size >= (size_t)253000000;
    __hip_bfloat16* e_b = big ? (__hip_bfloat16*)alloc((size_t)N_EDGES * DMODEL * 2) : nullptr;

    float* out_h    = (float*)d_out;
    float* out_glob = (float*)d_out + (size_t)N_NODES * DMODEL;

    // zero-init (ws/d_out are re-poisoned each call)
    hipMemsetAsync(counts, 0, (size_t)N_NODES * 4, stream);
    hipMemsetAsync(lnstat, 0, (size_t)3 * NLAYER * NGRAPH * 2 * 4, stream);
    hipMemsetAsync(out_glob, 0, (size_t)NGRAPH * DMODEL * 4, stream);

    // CSR build
    count_k<<<512, 256, 0, stream>>>(dst, counts);
    scan_k<<<1, 256, 0, stream>>>(counts, rowptr, cursor);
    fill_k<<<512, 256, 0, stream>>>(dst, cursor, elist);

    // embeddings (bf16 MFMA)
    if (big)
        bgemm_k<0, false, __hip_bfloat16><<<dim3(DMODEL / 128, N_EDGES / 128), 256, 0, stream>>>(
            N_EDGES, DMODEL, 64, edge_attr, nullptr, edge_emb_w, nullptr, e_b);
    bgemm_k<0, false, float><<<dim3(DMODEL / 128, N_NODES / 128), 256, 0, stream>>>(
        N_NODES, DMODEL, 128, x, nullptr, node_emb_w, nullptr, h);

    // graph-LN helper: stats + apply
    auto launch_ln = [&](const float* x1, const float* x2, const float* g_, const float* b_,
                         const float* addout, float* out, int slice) {
        float* st = lnstat + (size_t)slice * NGRAPH * 2;
        ln_stats_k<<<NGRAPH * 8, 256, 0, stream>>>(x1, x2, st);
        if (addout)
            ln_apply_k<true ><<<2048, 256, 0, stream>>>(x1, x2, g_, b_, addout, st, out);
        else
            ln_apply_k<false><<<2048, 256, 0, stream>>>(x1, x2, g_, b_, nullptr, st, out);
    };

    for (int l = 0; l < NLAYER; ++l) {
        const float* w1  = conv_w1 + (size_t)l * DMODEL * DMODEL;
        const float* b1  = conv_b1 + (size_t)l * DMODEL;
        const float* w2  = conv_w2 + (size_t)l * DMODEL * DMODEL;
        const float* b2  = conv_b2 + (size_t)l * DMODEL;
        const float* inw = attn_in_w + (size_t)l * 3 * DMODEL * DMODEL;
        const float* inb = attn_in_b + (size_t)l * 3 * DMODEL;
        const float* ow  = attn_out_w + (size_t)l * DMODEL * DMODEL;
        const float* ob  = attn_out_b + (size_t)l * DMODEL;
        const float* mw1 = mlp_w1 + (size_t)l * 2 * DMODEL * DMODEL;
        const float* mb1 = mlp_b1 + (size_t)l * 2 * DMODEL;
        const float* mw2 = mlp_w2 + (size_t)l * 2 * DMODEL * DMODEL;
        const float* mb2 = mlp_b2 + (size_t)l * DMODEL;

        // GINEConv
        if (big)
            agg_k<true ><<<N_NODES, 256, 0, stream>>>(h, e_b, edge_attr, edge_emb_w, src, rowptr, elist, bA);
        else
            agg_k<false><<<N_NODES, 256, 0, stream>>>(h, e_b, edge_attr, edge_emb_w, src, rowptr, elist, bA);
        bgemm_k<1, true, float><<<dim3(2, 128), 256, 0, stream>>>(
            N_NODES, DMODEL, DMODEL, h, bA, w1, b1, bB);                       // gelu((h+agg)@w1^T+b1)
        bgemm_k<0, false, float><<<dim3(2, 128), 256, 0, stream>>>(
            N_NODES, DMODEL, DMODEL, bB, nullptr, w2, b2, bA);                 // @w2^T+b2
        launch_ln(bA, h, n1_g + (size_t)l * DMODEL, n1_b + (size_t)l * DMODEL,
                  nullptr, bC, 3 * l + 0);                                      // h1 = LN(z + h)
        // attention
        bgemm_k<0, false, float><<<dim3(6, 128), 256, 0, stream>>>(
            N_NODES, 3 * DMODEL, DMODEL, h, nullptr, inw, inb, Q);             // qkv
        attn_k<<<NGRAPH * NHEAD, 256, 0, stream>>>(Q, bB);                     // attn (pre-proj)
        bgemm_k<0, false, float><<<dim3(2, 128), 256, 0, stream>>>(
            N_NODES, DMODEL, DMODEL, bB, nullptr, ow, ob, bA);                 // out-proj
        launch_ln(bA, h, n2_g + (size_t)l * DMODEL, n2_b + (size_t)l * DMODEL,
                  bC, h, 3 * l + 1);                                            // h = h1 + LN(a + h)
        // MLP
        bgemm_k<2, false, float><<<dim3(4, 128), 256, 0, stream>>>(
            N_NODES, 2 * DMODEL, DMODEL, h, nullptr, mw1, mb1, Q);             // relu(out@mw1^T+mb1)
        bgemm_k<0, false, float><<<dim3(2, 128), 256, 0, stream>>>(
            N_NODES, DMODEL, 2 * DMODEL, Q, nullptr, mw2, mb2, bA);            // @mw2^T+mb2
        float* ln3_out = (l == NLAYER - 1) ? out_h : h;                        // final writes d_out
        launch_ln(h, bA, n3_g + (size_t)l * DMODEL, n3_b + (size_t)l * DMODEL,
                  nullptr, ln3_out, 3 * l + 2);                                 // h = LN(out + mlp)
    }

    pool_k<<<NGRAPH * 4, 256, 0, stream>>>(out_h, out_glob);
}

// Round 11
// 1990.827 us; speedup vs baseline: 2.2968x; 1.1089x over previous
//
#include <hip/hip_runtime.h>
#include <hip/hip_bf16.h>

#define N_NODES 16384
#define N_EDGES 262144
#define NGRAPH  128
#define NPG     128
#define DMODEL  256
#define NLAYER  5
#define NHEAD   4
#define DHEAD   64

using short8 = __attribute__((ext_vector_type(8))) short;
using f32x4  = __attribute__((ext_vector_type(4))) float;

// ---------------- output convert helper ----------------
template<typename T> __device__ inline T cvt_out(float v);
template<> __device__ inline float cvt_out<float>(float v) { return v; }
template<> __device__ inline __hip_bfloat16 cvt_out<__hip_bfloat16>(float v) { return __float2bfloat16(v); }

__device__ inline short f2bf(float f) {
    __hip_bfloat16 b = __float2bfloat16(f);
    return *reinterpret_cast<short*>(&b);
}

__device__ inline float bf2f(unsigned short u) {
    unsigned int x = ((unsigned int)u) << 16;
    return *reinterpret_cast<float*>(&x);
}

// ---------------- bf16 MFMA GEMM: C[M,N] = act( (A (+A2)) @ W^T + bias ) ----------------
// A: [M,K] f32 row-major, W: [N,K] f32 row-major. M%128==0, N%128==0, K%64==0.
// 128x128 tile, BK=64, 4 waves (64x64 quadrant each), mfma_f32_16x16x32_bf16.
// LDS rows 128B, XOR-swizzle byte ^= (row&7)<<4 (T2) -> conflict-free ds_read_b128.
// ACT: 0=none, 1=GELU(erf), 2=ReLU
template<int ACT, bool FUSE, typename OutT>
__global__ __launch_bounds__(256) void bgemm_k(
    int M, int N, int K,
    const float* __restrict__ A, const float* __restrict__ A2,
    const float* __restrict__ W, const float* __restrict__ bias,
    OutT* __restrict__ C)
{
    __shared__ __align__(16) short Asw[128 * 64];
    __shared__ __align__(16) short Bsw[128 * 64];
    const int t = threadIdx.x;
    const int row0 = blockIdx.y * 128, col0 = blockIdx.x * 128;
    const int lane = t & 63;
    const int wave = t >> 6;
    const int wm = (wave >> 1) * 64, wn = (wave & 1) * 64;   // quadrant origin
    const int fr = lane & 15;        // fragment row/col
    const int kg = lane >> 4;        // k-group (0..3)

    f32x4 acc[4][4];
    #pragma unroll
    for (int mi = 0; mi < 4; ++mi)
        #pragma unroll
        for (int ni = 0; ni < 4; ++ni)
            acc[mi][ni] = (f32x4){0.f, 0.f, 0.f, 0.f};

    // staging assignment: row = t&127, k-half = (t>>7)*32 (32 f32 per thread per tile)
    const int srow = t & 127;
    const int sh   = (t >> 7) * 32;
    const int sxor = (srow & 7) << 4;

    for (int k0 = 0; k0 < K; k0 += 64) {
        // ---- stage A (f32 -> bf16, swizzled) ----
        {
            const float4* ga = reinterpret_cast<const float4*>(A + (size_t)(row0 + srow) * K + k0 + sh);
            float4 v[8];
            #pragma unroll
            for (int i = 0; i < 8; ++i) v[i] = ga[i];
            if (FUSE) {
                const float4* g2 = reinterpret_cast<const float4*>(A2 + (size_t)(row0 + srow) * K + k0 + sh);
                #pragma unroll
                for (int i = 0; i < 8; ++i) {
                    float4 w2 = g2[i];
                    v[i].x += w2.x; v[i].y += w2.y; v[i].z += w2.z; v[i].w += w2.w;
                }
            }
            #pragma unroll
            for (int c = 0; c < 4; ++c) {
                short8 s8;
                const float* pv = reinterpret_cast<const float*>(&v[c * 2]);
                #pragma unroll
                for (int e = 0; e < 8; ++e) s8[e] = f2bf(pv[e]);
                const int byte = (sh * 2 + c * 16) ^ sxor;
                *reinterpret_cast<short8*>(&Asw[srow * 64 + (byte >> 1)]) = s8;
            }
        }
        // ---- stage B (W rows) ----
        {
            const float4* gb = reinterpret_cast<const float4*>(W + (size_t)(col0 + srow) * K + k0 + sh);
            float4 v[8];
            #pragma unroll
            for (int i = 0; i < 8; ++i) v[i] = gb[i];
            #pragma unroll
            for (int c = 0; c < 4; ++c) {
                short8 s8;
                const float* pv = reinterpret_cast<const float*>(&v[c * 2]);
                #pragma unroll
                for (int e = 0; e < 8; ++e) s8[e] = f2bf(pv[e]);
                const int byte = (sh * 2 + c * 16) ^ sxor;
                *reinterpret_cast<short8*>(&Bsw[srow * 64 + (byte >> 1)]) = s8;
            }
        }
        __syncthreads();

        // ---- MFMA: 2 k-halves x 4x4 frags ----
        #pragma unroll
        for (int kh = 0; kh < 2; ++kh) {
            short8 af[4], bf_[4];
            #pragma unroll
            for (int mi = 0; mi < 4; ++mi) {
                const int row  = wm + mi * 16 + fr;
                const int byte = (kh * 64 + kg * 16) ^ ((row & 7) << 4);
                af[mi] = *reinterpret_cast<const short8*>(&Asw[row * 64 + (byte >> 1)]);
            }
            #pragma unroll
            for (int ni = 0; ni < 4; ++ni) {
                const int row  = wn + ni * 16 + fr;
                const int byte = (kh * 64 + kg * 16) ^ ((row & 7) << 4);
                bf_[ni] = *reinterpret_cast<const short8*>(&Bsw[row * 64 + (byte >> 1)]);
            }
            #pragma unroll
            for (int mi = 0; mi < 4; ++mi)
                #pragma unroll
                for (int ni = 0; ni < 4; ++ni)
                    acc[mi][ni] = __builtin_amdgcn_mfma_f32_16x16x32_bf16(
                        af[mi], bf_[ni], acc[mi][ni], 0, 0, 0);
        }
        __syncthreads();
    }

    // ---- epilogue: D row = kg*4+r (m), col = fr (n)  [m89/m91 mapping] ----
    #pragma unroll
    for (int mi = 0; mi < 4; ++mi) {
        #pragma unroll
        for (int ni = 0; ni < 4; ++ni) {
            const int col = col0 + wn + ni * 16 + fr;
            const float bv = bias ? bias[col] : 0.f;
            #pragma unroll
            for (int r = 0; r < 4; ++r) {
                const int row = row0 + wm + mi * 16 + kg * 4 + r;
                float v = acc[mi][ni][r] + bv;
                if (ACT == 1) v = 0.5f * v * (1.0f + erff(v * 0.70710678118654752f));
                if (ACT == 2) v = fmaxf(v, 0.f);
                C[(size_t)row * N + col] = cvt_out<OutT>(v);
            }
        }
    }
}

// ---------------- CSR build (by dst) ----------------
__global__ void count_k(const int* __restrict__ dst, int* __restrict__ counts)
{
    for (int i = blockIdx.x * blockDim.x + threadIdx.x; i < N_EDGES; i += gridDim.x * blockDim.x)
        atomicAdd(&counts[dst[i]], 1);
}

__global__ void scan_k(const int* __restrict__ counts, int* __restrict__ rowptr, int* __restrict__ cursor)
{
    __shared__ int part[256];
    __shared__ int base_s[257];
    const int t = threadIdx.x;
    int sum = 0;
    for (int i = 0; i < 64; ++i) sum += counts[t * 64 + i];
    part[t] = sum;
    __syncthreads();
    if (t == 0) {
        int acc = 0;
        for (int i = 0; i < 256; ++i) { base_s[i] = acc; acc += part[i]; }
        base_s[256] = acc;
    }
    __syncthreads();
    int run = base_s[t];
    for (int i = 0; i < 64; ++i) {
        const int idx = t * 64 + i;
        rowptr[idx] = run; cursor[idx] = run;
        run += counts[idx];
    }
    if (t == 255) rowptr[N_NODES] = base_s[256];
}

__global__ void fill_k(const int* __restrict__ dst, int* __restrict__ cursor, int* __restrict__ elist)
{
    for (int i = blockIdx.x * blockDim.x + threadIdx.x; i < N_EDGES; i += gridDim.x * blockDim.x) {
        const int p = atomicAdd(&cursor[dst[i]], 1);
        elist[p] = i;
    }
}

// ---------------- GINE aggregation (r10 rewrite): 4 edges in flight, wide loads ----------------
// agg[n,c] = sum_{e: dst=n} relu(h[src_e,c] + e_b[e,c]).
// Block = node. 4 x 64-lane groups each own edges i == g (mod 4); lane l covers cols 4l..4l+3.
// h: float4/lane (1KB/wave/edge), e_b: ushort4/lane (512B/wave/edge). LDS cross-group reduce.
template<bool PRE>
__global__ __launch_bounds__(256) void agg_k(
    const float* __restrict__ h, const __hip_bfloat16* __restrict__ e_b,
    const float* __restrict__ edge_attr, const float* __restrict__ We,
    const int* __restrict__ src, const int* __restrict__ rowptr,
    const int* __restrict__ elist, float* __restrict__ agg)
{
    const int n = blockIdx.x, t = threadIdx.x;
    const int beg = rowptr[n], deg = rowptr[n + 1] - beg;
    if (PRE) {
        __shared__ int eid_s[256];
        __shared__ int src_s[256];
        __shared__ float red[4 * 256];
        const int g = t >> 6, l = t & 63;
        f32x4 acc = (f32x4){0.f, 0.f, 0.f, 0.f};
        for (int base = 0; base < deg; base += 256) {     // single iter for deg<=256
            const int cnt = min(deg - base, 256);
            if (t < cnt) eid_s[t] = elist[beg + base + t];
            __syncthreads();
            if (t < cnt) src_s[t] = src[eid_s[t]];
            __syncthreads();
            for (int i = g; i < cnt; i += 4) {
                const int eid = eid_s[i];
                const int s   = src_s[i];
                const float4  hv = *reinterpret_cast<const float4*>(h + (size_t)s * DMODEL + l * 4);
                const ushort4 ev = *reinterpret_cast<const ushort4*>(
                    reinterpret_cast<const unsigned short*>(e_b) + (size_t)eid * DMODEL + l * 4);
                acc[0] += fmaxf(hv.x + bf2f(ev.x), 0.f);
                acc[1] += fmaxf(hv.y + bf2f(ev.y), 0.f);
                acc[2] += fmaxf(hv.z + bf2f(ev.z), 0.f);
                acc[3] += fmaxf(hv.w + bf2f(ev.w), 0.f);
            }
            __syncthreads();                              // protect eid_s reuse next chunk
        }
        *reinterpret_cast<f32x4*>(&red[t * 4]) = acc;     // red[g*256 + l*4 ..]
        __syncthreads();
        float s0 = red[t] + red[256 + t] + red[512 + t] + red[768 + t];
        agg[(size_t)n * DMODEL + t] = s0;
    } else {
        __shared__ float We_s[256][65];
        __shared__ float ea_s[64];
        float acc = 0.f;
        for (int idx = t; idx < 256 * 64; idx += 256)
            We_s[idx >> 6][idx & 63] = We[idx];
        __syncthreads();
        for (int j = beg; j < beg + deg; ++j) {
            const int eid = elist[j];
            const int s   = src[eid];
            if (t < 64) ea_s[t] = edge_attr[(size_t)eid * 64 + t];
            __syncthreads();
            float dot = 0.f;
            #pragma unroll
            for (int k = 0; k < 64; ++k) dot += ea_s[k] * We_s[t][k];
            acc += fmaxf(h[(size_t)s * DMODEL + t] + dot, 0.f);
            __syncthreads();
        }
        agg[(size_t)n * DMODEL + t] = acc;
    }
}

// ---------------- graph LayerNorm, split stats/apply ----------------
__global__ __launch_bounds__(256) void ln_stats_k(
    const float* __restrict__ x1, const float* __restrict__ x2,
    float* __restrict__ stat)
{
    const int blk = blockIdx.x;          // g*8 + slice
    const int g = blk >> 3, sl = blk & 7;
    const int t = threadIdx.x;
    const float4* p1 = reinterpret_cast<const float4*>(x1) + (size_t)g * 8192 + sl * 1024;
    const float4* p2 = reinterpret_cast<const float4*>(x2) + (size_t)g * 8192 + sl * 1024;
    float s = 0.f, ss = 0.f;
    #pragma unroll
    for (int k = 0; k < 4; ++k) {
        const float4 a = p1[t + k * 256];
        const float4 b = p2[t + k * 256];
        const float v0 = a.x + b.x, v1 = a.y + b.y, v2 = a.z + b.z, v3 = a.w + b.w;
        s  += v0 + v1 + v2 + v3;
        ss += v0 * v0 + v1 * v1 + v2 * v2 + v3 * v3;
    }
    __shared__ float rs[256], rq[256];
    rs[t] = s; rq[t] = ss;
    __syncthreads();
    if (t < 128) { rs[t] += rs[t + 128]; rq[t] += rq[t + 128]; }
    __syncthreads();
    if (t < 64) {
        float a = rs[t] + rs[t + 64];
        float b = rq[t] + rq[t + 64];
        #pragma unroll
        for (int off = 32; off > 0; off >>= 1) {
            a += __shfl_down(a, off);
            b += __shfl_down(b, off);
        }
        if (t == 0) { atomicAdd(&stat[g * 2 + 0], a); atomicAdd(&stat[g * 2 + 1], b); }
    }
}

template<bool ADD>
__global__ __launch_bounds__(256) void ln_apply_k(
    const float* __restrict__ x1, const float* __restrict__ x2,
    const float* __restrict__ gamma, const float* __restrict__ beta,
    const float* __restrict__ addout, const float* __restrict__ stat,
    float* __restrict__ out)
{
    const int F = N_NODES * DMODEL / 4;
    const float4* p1 = reinterpret_cast<const float4*>(x1);
    const float4* p2 = reinterpret_cast<const float4*>(x2);
    const float4* pg = reinterpret_cast<const float4*>(gamma);
    const float4* pb = reinterpret_cast<const float4*>(beta);
    const float4* pa = ADD ? reinterpret_cast<const float4*>(addout) : nullptr;
    float4* po = reinterpret_cast<float4*>(out);
    const float inv = 1.f / (NPG * DMODEL);
    for (int f = blockIdx.x * 256 + threadIdx.x; f < F; f += gridDim.x * 256) {
        const int g = f >> 13;
        const float mu   = stat[g * 2 + 0] * inv;
        const float var  = stat[g * 2 + 1] * inv - mu * mu;
        const float rstd = rsqrtf(var + 1e-5f);
        const float4 a = p1[f], b = p2[f];
        const float4 gm = pg[f & 63], bt = pb[f & 63];
        float4 y;
        y.x = (a.x + b.x - mu) * rstd * gm.x + bt.x;
        y.y = (a.y + b.y - mu) * rstd * gm.y + bt.y;
        y.z = (a.z + b.z - mu) * rstd * gm.z + bt.z;
        y.w = (a.w + b.w - mu) * rstd * gm.w + bt.w;
        if (ADD) {
            const float4 ao = pa[f];
            y.x += ao.x; y.y += ao.y; y.z += ao.z; y.w += ao.w;
        }
        po[f] = y;
    }
}

// ---------------- per-(graph,head) attention ----------------
__global__ __launch_bounds__(256) void attn_k(const float* __restrict__ qkv, float* __restrict__ attnout)
{
    __shared__ float s_s[128][129];
    __shared__ float q_s[128][65];
    __shared__ float kv_s[128][65];
    const int blk = blockIdx.x;
    const int b = blk >> 2, hh = blk & 3;
    const int t = threadIdx.x;
    const size_t base = (size_t)b * NPG * (3 * DMODEL) + hh * DHEAD;

    for (int l = t; l < 128 * 64; l += 256) {
        const int r = l >> 6, c = l & 63;
        q_s[r][c]  = qkv[base + (size_t)r * 768 + c];
        kv_s[r][c] = qkv[base + 256 + (size_t)r * 768 + c];
    }
    __syncthreads();

    #pragma unroll
    for (int it = 0; it < 4; ++it) {
        const int tt = t + 256 * it;
        const int tr = (tt & 31) * 4;
        const int tc = (tt >> 5) * 4;
        float acc[4][4];
        #pragma unroll
        for (int i = 0; i < 4; ++i)
            #pragma unroll
            for (int j = 0; j < 4; ++j) acc[i][j] = 0.f;
        for (int d = 0; d < 64; ++d) {
            float qa[4], kb[4];
            #pragma unroll
            for (int i = 0; i < 4; ++i) qa[i] = q_s[tr + i][d];
            #pragma unroll
            for (int j = 0; j < 4; ++j) kb[j] = kv_s[tc + j][d];
            #pragma unroll
            for (int i = 0; i < 4; ++i)
                #pragma unroll
                for (int j = 0; j < 4; ++j) acc[i][j] += qa[i] * kb[j];
        }
        #pragma unroll
        for (int i = 0; i < 4; ++i)
            #pragma unroll
            for (int j = 0; j < 4; ++j) s_s[tr + i][tc + j] = acc[i][j] * 0.125f;
    }
    __syncthreads();

    {
        const int r = t >> 1, ch = (t & 1) * 64;
        float mx = -1e30f;
        for (int cc = 0; cc < 64; ++cc) mx = fmaxf(mx, s_s[r][ch + cc]);
        mx = fmaxf(mx, __shfl_xor(mx, 1));
        float sum = 0.f;
        for (int cc = 0; cc < 64; ++cc) {
            const float pv = expf(s_s[r][ch + cc] - mx);
            s_s[r][ch + cc] = pv; sum += pv;
        }
        sum += __shfl_xor(sum, 1);
        const float inv = 1.f / sum;
        for (int cc = 0; cc < 64; ++cc) s_s[r][ch + cc] *= inv;
    }
    __syncthreads();

    for (int l = t; l < 128 * 64; l += 256) {
        const int r = l >> 6, c = l & 63;
        kv_s[r][c] = qkv[base + 512 + (size_t)r * 768 + c];
    }
    __syncthreads();

    #pragma unroll
    for (int it = 0; it < 2; ++it) {
        const int tt  = t + 256 * it;
        const int tr  = (tt & 31) * 4;
        const int tdh = (tt >> 5) * 4;
        float acc[4][4];
        #pragma unroll
        for (int i = 0; i < 4; ++i)
            #pragma unroll
            for (int j = 0; j < 4; ++j) acc[i][j] = 0.f;
        for (int c = 0; c < 128; ++c) {
            float pa[4], vb[4];
            #pragma unroll
            for (int i = 0; i < 4; ++i) pa[i] = s_s[tr + i][c];
            #pragma unroll
            for (int j = 0; j < 4; ++j) vb[j] = kv_s[c][tdh + j];
            #pragma unroll
            for (int i = 0; i < 4; ++i)
                #pragma unroll
                for (int j = 0; j < 4; ++j) acc[i][j] += pa[i] * vb[j];
        }
        #pragma unroll
        for (int i = 0; i < 4; ++i) {
            float* op = attnout + ((size_t)(b * NPG + tr + i)) * DMODEL + hh * DHEAD + tdh;
            #pragma unroll
            for (int j = 0; j < 4; ++j) op[j] = acc[i][j];
        }
    }
}

// ---------------- global_add_pool ----------------
__global__ __launch_bounds__(256) void pool_k(const float* __restrict__ h, float* __restrict__ glob)
{
    const int blk = blockIdx.x;
    const int g = blk >> 2, q = blk & 3;
    const int d = threadIdx.x;
    const float* base = h + ((size_t)g * NPG + q * 32) * DMODEL + d;
    float s = 0.f;
    #pragma unroll
    for (int n = 0; n < 32; ++n) s += base[(size_t)n * DMODEL];
    atomicAdd(&glob[g * DMODEL + d], s);
}

// ---------------- launch ----------------
extern "C" void kernel_launch(void* const* d_in, const int* in_sizes, int n_in,
                              void* d_out, int out_size, void* d_ws, size_t ws_size,
                              hipStream_t stream)
{
    const float* x          = (const float*)d_in[0];
    const float* edge_attr  = (const float*)d_in[1];
    const int*   eidx       = (const int*)d_in[2];
    const float* node_emb_w = (const float*)d_in[4];
    const float* edge_emb_w = (const float*)d_in[5];
    const float* conv_w1    = (const float*)d_in[6];
    const float* conv_b1    = (const float*)d_in[7];
    const float* conv_w2    = (const float*)d_in[8];
    const float* conv_b2    = (const float*)d_in[9];
    const float* attn_in_w  = (const float*)d_in[10];
    const float* attn_in_b  = (const float*)d_in[11];
    const float* attn_out_w = (const float*)d_in[12];
    const float* attn_out_b = (const float*)d_in[13];
    const float* n1_g = (const float*)d_in[14];
    const float* n1_b = (const float*)d_in[15];
    const float* n2_g = (const float*)d_in[16];
    const float* n2_b = (const float*)d_in[17];
    const float* n3_g = (const float*)d_in[18];
    const float* n3_b = (const float*)d_in[19];
    const float* mlp_w1 = (const float*)d_in[20];
    const float* mlp_b1 = (const float*)d_in[21];
    const float* mlp_w2 = (const float*)d_in[22];
    const float* mlp_b2 = (const float*)d_in[23];
    const int* src = eidx;
    const int* dst = eidx + N_EDGES;

    char* p = (char*)d_ws;
    auto alloc = [&](size_t bytes) -> void* {
        void* r = (void*)p;
        p += (bytes + 255) & ~(size_t)255;
        return r;
    };
    // Mandatory buffers: ~113 MiB total
    float* h  = (float*)alloc((size_t)N_NODES * DMODEL * 4);
    float* bA = (float*)alloc((size_t)N_NODES * DMODEL * 4);
    float* bB = (float*)alloc((size_t)N_NODES * DMODEL * 4);
    float* bC = (float*)alloc((size_t)N_NODES * DMODEL * 4);
    float* Q  = (float*)alloc((size_t)N_NODES * 3 * DMODEL * 4);   // qkv; also mlp-mid [N,512]
    int* counts = (int*)alloc((size_t)N_NODES * 4);
    int* rowptr = (int*)alloc((size_t)(N_NODES + 1) * 4);
    int* cursor = (int*)alloc((size_t)N_NODES * 4);
    int* elist  = (int*)alloc((size_t)N_EDGES * 4);
    float* lnstat = (float*)alloc((size_t)3 * NLAYER * NGRAPH * 2 * 4);  // 15 LN slices
    // Optional 128 MiB edge-embedding cache (deterministic branch on ws_size).
    const bool big = ws_size >= (size_t)253000000;
    __hip_bfloat16* e_b = big ? (__hip_bfloat16*)alloc((size_t)N_EDGES * DMODEL * 2) : nullptr;

    float* out_h    = (float*)d_out;
    float* out_glob = (float*)d_out + (size_t)N_NODES * DMODEL;

    // zero-init (ws/d_out are re-poisoned each call)
    hipMemsetAsync(counts, 0, (size_t)N_NODES * 4, stream);
    hipMemsetAsync(lnstat, 0, (size_t)3 * NLAYER * NGRAPH * 2 * 4, stream);
    hipMemsetAsync(out_glob, 0, (size_t)NGRAPH * DMODEL * 4, stream);

    // CSR build
    count_k<<<512, 256, 0, stream>>>(dst, counts);
    scan_k<<<1, 256, 0, stream>>>(counts, rowptr, cursor);
    fill_k<<<512, 256, 0, stream>>>(dst, cursor, elist);

    // embeddings (bf16 MFMA)
    if (big)
        bgemm_k<0, false, __hip_bfloat16><<<dim3(DMODEL / 128, N_EDGES / 128), 256, 0, stream>>>(
            N_EDGES, DMODEL, 64, edge_attr, nullptr, edge_emb_w, nullptr, e_b);
    bgemm_k<0, false, float><<<dim3(DMODEL / 128, N_NODES / 128), 256, 0, stream>>>(
        N_NODES, DMODEL, 128, x, nullptr, node_emb_w, nullptr, h);

    // graph-LN helper: stats + apply
    auto launch_ln = [&](const float* x1, const float* x2, const float* g_, const float* b_,
                         const float* addout, float* out, int slice) {
        float* st = lnstat + (size_t)slice * NGRAPH * 2;
        ln_stats_k<<<NGRAPH * 8, 256, 0, stream>>>(x1, x2, st);
        if (addout)
            ln_apply_k<true ><<<2048, 256, 0, stream>>>(x1, x2, g_, b_, addout, st, out);
        else
            ln_apply_k<false><<<2048, 256, 0, stream>>>(x1, x2, g_, b_, nullptr, st, out);
    };

    for (int l = 0; l < NLAYER; ++l) {
        const float* w1  = conv_w1 + (size_t)l * DMODEL * DMODEL;
        const float* b1  = conv_b1 + (size_t)l * DMODEL;
        const float* w2  = conv_w2 + (size_t)l * DMODEL * DMODEL;
        const float* b2  = conv_b2 + (size_t)l * DMODEL;
        const float* inw = attn_in_w + (size_t)l * 3 * DMODEL * DMODEL;
        const float* inb = attn_in_b + (size_t)l * 3 * DMODEL;
        const float* ow  = attn_out_w + (size_t)l * DMODEL * DMODEL;
        const float* ob  = attn_out_b + (size_t)l * DMODEL;
        const float* mw1 = mlp_w1 + (size_t)l * 2 * DMODEL * DMODEL;
        const float* mb1 = mlp_b1 + (size_t)l * 2 * DMODEL;
        const float* mw2 = mlp_w2 + (size_t)l * 2 * DMODEL * DMODEL;
        const float* mb2 = mlp_b2 + (size_t)l * DMODEL;

        // GINEConv
        if (big)
            agg_k<true ><<<N_NODES, 256, 0, stream>>>(h, e_b, edge_attr, edge_emb_w, src, rowptr, elist, bA);
        else
            agg_k<false><<<N_NODES, 256, 0, stream>>>(h, e_b, edge_attr, edge_emb_w, src, rowptr, elist, bA);
        bgemm_k<1, true, float><<<dim3(2, 128), 256, 0, stream>>>(
            N_NODES, DMODEL, DMODEL, h, bA, w1, b1, bB);                       // gelu((h+agg)@w1^T+b1)
        bgemm_k<0, false, float><<<dim3(2, 128), 256, 0, stream>>>(
            N_NODES, DMODEL, DMODEL, bB, nullptr, w2, b2, bA);                 // @w2^T+b2
        launch_ln(bA, h, n1_g + (size_t)l * DMODEL, n1_b + (size_t)l * DMODEL,
                  nullptr, bC, 3 * l + 0);                                      // h1 = LN(z + h)
        // attention
        bgemm_k<0, false, float><<<dim3(6, 128), 256, 0, stream>>>(
            N_NODES, 3 * DMODEL, DMODEL, h, nullptr, inw, inb, Q);             // qkv
        attn_k<<<NGRAPH * NHEAD, 256, 0, stream>>>(Q, bB);                     // attn (pre-proj)
        bgemm_k<0, false, float><<<dim3(2, 128), 256, 0, stream>>>(
            N_NODES, DMODEL, DMODEL, bB, nullptr, ow, ob, bA);                 // out-proj
        launch_ln(bA, h, n2_g + (size_t)l * DMODEL, n2_b + (size_t)l * DMODEL,
                  bC, h, 3 * l + 1);                                            // h = h1 + LN(a + h)
        // MLP
        bgemm_k<2, false, float><<<dim3(4, 128), 256, 0, stream>>>(
            N_NODES, 2 * DMODEL, DMODEL, h, nullptr, mw1, mb1, Q);             // relu(out@mw1^T+mb1)
        bgemm_k<0, false, float><<<dim3(2, 128), 256, 0, stream>>>(
            N_NODES, DMODEL, 2 * DMODEL, Q, nullptr, mw2, mb2, bA);            // @mw2^T+mb2
        float* ln3_out = (l == NLAYER - 1) ? out_h : h;                        // final writes d_out
        launch_ln(h, bA, n3_g + (size_t)l * DMODEL, n3_b + (size_t)l * DMODEL,
                  nullptr, ln3_out, 3 * l + 2);                                 // h = LN(out + mlp)
    }

    pool_k<<<NGRAPH * 4, 256, 0, stream>>>(out_h, out_glob);
}